// Round 1
// baseline (954.606 us; speedup 1.0000x reference)
//
#include <hip/hip_runtime.h>
#include <math.h>

// Problem: B=16, C=512, R=32, PS=3, HN=8, D=128, H=W=96.
#define NB 16
#define BSTR 524288            // C*R*R floats per batch in pooled buffers

// workspace layout (floats)
#define OFF_QPOOL 0ull
#define OFF_KPOOL 8388608ull
#define OFF_VPOOL 16777216ull
#define OFF_QPROJ 25165824ull
#define OFF_KPROJ 33554432ull
#define OFF_KBAR  41943040ull   // 128*128 per (b,h): 16384
#define OFF_MROW  41959424ull   // 65536
#define OFF_IPW   42024960ull   // 65536
#define OFF_SC    42090496ull   // score slices: group*8? -> group_bh*512*512

// ---------------- K1: fused avg+max 3x3 pool ----------------
__global__ __launch_bounds__(256) void pool_kernel(const float* __restrict__ x,
                                                   float* __restrict__ qp,
                                                   float* __restrict__ kp) {
    int idx = blockIdx.x * 256 + threadIdx.x;      // < 8388608
    int r = idx & 1023;
    int c = (idx >> 10) & 511;
    int b = idx >> 19;
    int i = r >> 5, j = r & 31;
    const float* p = x + b * 4718592 + c * 9216 + (3 * i) * 96 + 3 * j;
    float s = 0.f, mx = -INFINITY;
    #pragma unroll
    for (int di = 0; di < 3; ++di) {
        #pragma unroll
        for (int dj = 0; dj < 3; ++dj) {
            float v = p[di * 96 + dj];
            s += v;
            mx = fmaxf(mx, v);
        }
    }
    qp[idx] = s * (1.f / 9.f);
    kp[idx] = mx;
}

// shared inner-product microkernel (4x4 per thread, float4 LDS reads)
#define MICRO_LOOP()                                                                   \
    _Pragma("unroll")                                                                  \
    for (int kk = 0; kk < 32; ++kk) {                                                  \
        const float4 a4 = *(const float4*)&As[kk][tm * 4];                             \
        const float4 b4 = *(const float4*)&Bs[kk][tn * 4];                             \
        acc[0][0] += a4.x * b4.x; acc[0][1] += a4.x * b4.y;                            \
        acc[0][2] += a4.x * b4.z; acc[0][3] += a4.x * b4.w;                            \
        acc[1][0] += a4.y * b4.x; acc[1][1] += a4.y * b4.y;                            \
        acc[1][2] += a4.y * b4.z; acc[1][3] += a4.y * b4.w;                            \
        acc[2][0] += a4.z * b4.x; acc[2][1] += a4.z * b4.y;                            \
        acc[2][2] += a4.z * b4.z; acc[2][3] += a4.z * b4.w;                            \
        acc[3][0] += a4.w * b4.x; acc[3][1] += a4.w * b4.y;                            \
        acc[3][2] += a4.w * b4.z; acc[3][3] += a4.w * b4.w;                            \
    }

// ---------------- K2: Vpool[b,o,r] = bv[o] + sum_c Wv[o,c]*Qpool[b,c,r] ----------------
__global__ __launch_bounds__(256) void vpool_gemm(const float* __restrict__ Wv,
                                                  const float* __restrict__ bv,
                                                  const float* __restrict__ qp,
                                                  float* __restrict__ vp) {
    __shared__ float As[32][68];
    __shared__ float Bs[32][68];
    const int tid = threadIdx.x;
    const int n0 = blockIdx.x * 64;   // r
    const int m0 = blockIdx.y * 64;   // o
    const int b  = blockIdx.z;
    const int tm = tid & 15, tn = tid >> 4;
    float acc[4][4] = {{0.f}};
    const float* Bb = qp + b * BSTR;
    for (int k0 = 0; k0 < 512; k0 += 32) {
        #pragma unroll
        for (int t = 0; t < 8; ++t) {
            int idx = tid + t * 256;
            As[idx & 31][idx >> 5] = Wv[(m0 + (idx >> 5)) * 512 + k0 + (idx & 31)];
        }
        #pragma unroll
        for (int t = 0; t < 8; ++t) {
            int idx = tid + t * 256;
            Bs[idx >> 6][idx & 63] = Bb[(k0 + (idx >> 6)) * 1024 + n0 + (idx & 63)];
        }
        __syncthreads();
        MICRO_LOOP();
        __syncthreads();
    }
    #pragma unroll
    for (int i = 0; i < 4; ++i) {
        int m = m0 + tm * 4 + i;
        float bias = bv[m];
        *(float4*)&vp[b * BSTR + m * 1024 + n0 + tn * 4] =
            make_float4(acc[i][0] + bias, acc[i][1] + bias, acc[i][2] + bias, acc[i][3] + bias);
    }
}

// ---------------- K3: per-(b,h) projection of Q and K head chunks ----------------
// out[c,e] = bqk[h,e] + sum_d A[d,c]*Wqk[h,e,d];  A = pool_flat + b*BSTR + h*65536, [128][512]
__global__ __launch_bounds__(256) void proj_gemm(const float* __restrict__ qp,
                                                 const float* __restrict__ kp,
                                                 const float* __restrict__ Wqk,
                                                 const float* __restrict__ bqk,
                                                 float* __restrict__ pq,
                                                 float* __restrict__ pk) {
    __shared__ float As[32][68];
    __shared__ float Bs[32][68];
    const int tid = threadIdx.x;
    const int n0 = blockIdx.x * 64;   // e (0 or 64)
    const int m0 = blockIdx.y * 64;   // c
    const int z  = blockIdx.z;        // b*16 + h*2 + src
    const int b = z >> 4, h = (z >> 1) & 7, src = z & 1;
    const float* A = (src ? kp : qp) + b * BSTR + h * 65536;
    float* outp = (src ? pk : pq) + (b * 8 + h) * 65536;
    const float* W = Wqk + h * 16384;
    const int tm = tid & 15, tn = tid >> 4;
    float acc[4][4] = {{0.f}};
    for (int k0 = 0; k0 < 128; k0 += 32) {
        #pragma unroll
        for (int t = 0; t < 8; ++t) {
            int idx = tid + t * 256;
            As[idx >> 6][idx & 63] = A[(k0 + (idx >> 6)) * 512 + m0 + (idx & 63)];
        }
        #pragma unroll
        for (int t = 0; t < 8; ++t) {
            int idx = tid + t * 256;
            Bs[idx & 31][idx >> 5] = W[(n0 + (idx >> 5)) * 128 + k0 + (idx & 31)];
        }
        __syncthreads();
        MICRO_LOOP();
        __syncthreads();
    }
    #pragma unroll
    for (int i = 0; i < 4; ++i) {
        int m = m0 + tm * 4 + i;
        int n = n0 + tn * 4;
        const float4 bias = *(const float4*)&bqk[h * 128 + n];
        *(float4*)&outp[m * 128 + n] =
            make_float4(acc[i][0] + bias.x, acc[i][1] + bias.y, acc[i][2] + bias.z, acc[i][3] + bias.w);
    }
}

// ---------------- G1: kbar[bh,d] = mean_e Kproj[bh,e,d] ----------------
__global__ __launch_bounds__(128) void kbar_kernel(const float* __restrict__ pk,
                                                   float* __restrict__ kbar) {
    int bh = blockIdx.x, d = threadIdx.x;
    const float* p = pk + bh * 65536 + d;
    float s = 0.f;
    for (int e = 0; e < 512; ++e) s += p[e * 128];
    kbar[bh * 128 + d] = s * (1.f / 512.f);
}

// ---------------- G2: mrow[bh,c] = dot(Qproj[bh,c,:], kbar[bh,:]) ----------------
__global__ __launch_bounds__(256) void mrow_kernel(const float* __restrict__ pq,
                                                   const float* __restrict__ kbar,
                                                   float* __restrict__ mrow) {
    __shared__ float kb[128];
    int bh = blockIdx.x, tid = threadIdx.x;
    if (tid < 128) kb[tid] = kbar[bh * 128 + tid];
    __syncthreads();
    for (int c = tid; c < 512; c += 256) {
        const float* q = pq + (bh * 512 + c) * 128;
        float s = 0.f;
        #pragma unroll 8
        for (int d = 0; d < 128; ++d) s += q[d] * kb[d];
        mrow[bh * 512 + c] = s;
    }
}

// ---------------- G3: ipw[bh,c2] = 128^-(0.5 + sigmoid(mrow@Wp^T + bp)) ----------------
__global__ __launch_bounds__(256) void gate_kernel(const float* __restrict__ mrow,
                                                   const float* __restrict__ Wp,
                                                   const float* __restrict__ bp,
                                                   float* __restrict__ ipw) {
    __shared__ float ms[512];
    int bh = blockIdx.x, tid = threadIdx.x;
    for (int c = tid; c < 512; c += 256) ms[c] = mrow[bh * 512 + c];
    __syncthreads();
    for (int c2 = tid; c2 < 512; c2 += 256) {
        const float* wr = Wp + c2 * 512;
        float a = bp[c2];
        #pragma unroll 8
        for (int c = 0; c < 512; ++c) a += ms[c] * wr[c];
        float pg = 1.f / (1.f + expf(-a));
        ipw[bh * 512 + c2] = exp2f(-7.f * (0.5f + pg));   // 128^-(0.5+p)
    }
}

// ---------------- K5a: scores[c,e] = dot(Qproj[bh,c,:], Kproj[bh,e,:]) ----------------
__global__ __launch_bounds__(256) void scores_gemm(const float* __restrict__ pq,
                                                   const float* __restrict__ pk,
                                                   float* __restrict__ sc, int bh0) {
    __shared__ float As[32][68];
    __shared__ float Bs[32][68];
    const int tid = threadIdx.x;
    const int n0 = blockIdx.x * 64;   // e
    const int m0 = blockIdx.y * 64;   // c
    const int zl = blockIdx.z;
    const int bh = bh0 + zl;
    const float* Aq = pq + bh * 65536;
    const float* Bk = pk + bh * 65536;
    const int tm = tid & 15, tn = tid >> 4;
    float acc[4][4] = {{0.f}};
    for (int k0 = 0; k0 < 128; k0 += 32) {
        #pragma unroll
        for (int t = 0; t < 8; ++t) {
            int idx = tid + t * 256;
            As[idx & 31][idx >> 5] = Aq[(m0 + (idx >> 5)) * 128 + k0 + (idx & 31)];
        }
        #pragma unroll
        for (int t = 0; t < 8; ++t) {
            int idx = tid + t * 256;
            Bs[idx & 31][idx >> 5] = Bk[(n0 + (idx >> 5)) * 128 + k0 + (idx & 31)];
        }
        __syncthreads();
        MICRO_LOOP();
        __syncthreads();
    }
    float* op = sc + (size_t)zl * 262144;
    #pragma unroll
    for (int i = 0; i < 4; ++i)
        *(float4*)&op[(m0 + tm * 4 + i) * 512 + n0 + tn * 4] =
            make_float4(acc[i][0], acc[i][1], acc[i][2], acc[i][3]);
}

// ---------------- K5b: row softmax with per-row power normalization ----------------
// divisor >= 128^0.5 bounds |norm_scores| ~< 35 -> no overflow, max-subtraction skipped.
__global__ __launch_bounds__(256) void softmax_kernel(float* __restrict__ sc,
                                                      const float* __restrict__ ipw, int bh0) {
    const int tid = threadIdx.x;
    const int rowb = blockIdx.x * 4 + (tid >> 6);
    const int lane = tid & 63;
    const int zl = rowb >> 9, c = rowb & 511;
    float* rp = sc + (size_t)zl * 262144 + c * 512;
    const float scale = ipw[(bh0 + zl) * 512 + c];
    float4 v0 = *(float4*)(rp + lane * 8);
    float4 v1 = *(float4*)(rp + lane * 8 + 4);
    float e0 = expf(v0.x * scale), e1 = expf(v0.y * scale);
    float e2 = expf(v0.z * scale), e3 = expf(v0.w * scale);
    float e4 = expf(v1.x * scale), e5 = expf(v1.y * scale);
    float e6 = expf(v1.z * scale), e7 = expf(v1.w * scale);
    float s = ((e0 + e1) + (e2 + e3)) + ((e4 + e5) + (e6 + e7));
    #pragma unroll
    for (int off = 32; off; off >>= 1) s += __shfl_down(s, off);
    s = __shfl(s, 0);
    float inv = 1.f / s;
    *(float4*)(rp + lane * 8)     = make_float4(e0 * inv, e1 * inv, e2 * inv, e3 * inv);
    *(float4*)(rp + lane * 8 + 4) = make_float4(e4 * inv, e5 * inv, e6 * inv, e7 * inv);
}

// ---------------- K5c: attn = w @ Vh^T, + residual, scattered to output layout ----------------
__global__ __launch_bounds__(256) void attn_out_gemm(const float* __restrict__ sc,
                                                     const float* __restrict__ vp,
                                                     const float* __restrict__ qp,
                                                     float* __restrict__ outp,
                                                     const int* __restrict__ wgt, int bh0) {
    __shared__ float As[32][68];
    __shared__ float Bs[32][68];
    const int tid = threadIdx.x;
    const int n0 = blockIdx.x * 64;   // d (0 or 64)
    const int m0 = blockIdx.y * 64;   // c
    const int zl = blockIdx.z;
    const int bh = bh0 + zl;
    const int b = bh >> 3, h = bh & 7;
    const float* Aw = sc + (size_t)zl * 262144;   // [512 c][512 e]
    const float* Bv = vp + b * BSTR + h * 65536;  // [128 d][512 e]
    const int tm = tid & 15, tn = tid >> 4;
    float acc[4][4] = {{0.f}};
    for (int k0 = 0; k0 < 512; k0 += 32) {
        #pragma unroll
        for (int t = 0; t < 8; ++t) {
            int idx = tid + t * 256;
            As[idx & 31][idx >> 5] = Aw[(m0 + (idx >> 5)) * 512 + k0 + (idx & 31)];
        }
        #pragma unroll
        for (int t = 0; t < 8; ++t) {
            int idx = tid + t * 256;
            Bs[idx & 31][idx >> 5] = Bv[(n0 + (idx >> 5)) * 512 + k0 + (idx & 31)];
        }
        __syncthreads();
        MICRO_LOOP();
        __syncthreads();
    }
    const float mult = 1.f + (float)wgt[0];
    #pragma unroll
    for (int i = 0; i < 4; ++i) {
        int m = m0 + tm * 4 + i;
        #pragma unroll
        for (int j = 0; j < 4; ++j) {
            int n = n0 + tn * 4 + j;
            int o = b * BSTR + (h * 128 + n) * 512 + m;
            outp[o] = qp[o] + mult * acc[i][j];
        }
    }
}

extern "C" void kernel_launch(void* const* d_in, const int* in_sizes, int n_in,
                              void* d_out, int out_size, void* d_ws, size_t ws_size,
                              hipStream_t stream) {
    const float* x   = (const float*)d_in[0];
    const float* Wqk = (const float*)d_in[1];
    const float* bqk = (const float*)d_in[2];
    const float* Wp  = (const float*)d_in[3];
    const float* bp  = (const float*)d_in[4];
    const float* Wv  = (const float*)d_in[5];
    const float* bv  = (const float*)d_in[6];
    const int*   wgt = (const int*)d_in[7];
    float* out = (float*)d_out;

    float* ws   = (float*)d_ws;
    float* qp   = ws + OFF_QPOOL;
    float* kp   = ws + OFF_KPOOL;
    float* vp   = ws + OFF_VPOOL;
    float* pq   = ws + OFF_QPROJ;
    float* pk   = ws + OFF_KPROJ;
    float* kbar = ws + OFF_KBAR;
    float* mrow = ws + OFF_MROW;
    float* ipw  = ws + OFF_IPW;
    float* sc   = ws + OFF_SC;

    pool_kernel<<<32768, 256, 0, stream>>>(x, qp, kp);
    vpool_gemm<<<dim3(16, 8, NB), 256, 0, stream>>>(Wv, bv, qp, vp);
    proj_gemm<<<dim3(2, 8, 256), 256, 0, stream>>>(qp, kp, Wqk, bqk, pq, pk);
    kbar_kernel<<<128, 128, 0, stream>>>(pk, kbar);
    mrow_kernel<<<128, 256, 0, stream>>>(pq, kbar, mrow);
    gate_kernel<<<128, 256, 0, stream>>>(mrow, Wp, bp, ipw);

    // size the score slice to whatever scratch remains (same every call: ws_size is fixed)
    long long availf = (long long)(ws_size / 4) - (long long)OFF_SC;
    int group = (int)(availf / 262144LL);
    if (group > 128) group = 128;
    if (group < 1) group = 1;
    for (int bh0 = 0; bh0 < 128; bh0 += group) {
        int g = (128 - bh0 < group) ? (128 - bh0) : group;
        scores_gemm<<<dim3(8, 8, g), 256, 0, stream>>>(pq, pk, sc, bh0);
        softmax_kernel<<<g * 128, 256, 0, stream>>>(sc, ipw, bh0);
        attn_out_gemm<<<dim3(2, 8, g), 256, 0, stream>>>(sc, vp, qp, out, wgt, bh0);
    }
}

// Round 2
// 632.941 us; speedup vs baseline: 1.5082x; 1.5082x over previous
//
#include <hip/hip_runtime.h>
#include <math.h>

// Problem: B=16, C=512, R=32, PS=3, HN=8, D=128, H=W=96.
typedef unsigned short u16;
typedef short bf16x8 __attribute__((ext_vector_type(8)));
typedef float floatx4 __attribute__((ext_vector_type(4)));

// ---- workspace layout ----
// floats:
#define F_QP   0ull
#define F_KP   8388608ull
#define F_KBAR 16777216ull
#define F_MROW 16793600ull
#define F_IPW  16859136ull
#define F_RS   16924672ull     // rowsum [128][512]
#define F_END  16990208ull
// ushorts (base = (u16*)(ws + F_END)):
#define U_QPT_V 0ull           // [b][r=1024][c=512]   transpose of physical [c][r]
#define U_QPT_P 8388608ull     // [b][c=512][s=1024]   transpose of view [s][c]
#define U_KPT_P 16777216ull
#define U_PQ    25165824ull    // [bh][c=512][e=128]
#define U_PK    33554432ull
#define U_VP    41943040ull    // [b] linear [o=512][r=1024]
#define U_E     50331648ull    // [bh][c=512][e=512] exp(score*ipw), unnormalized
#define U_WV    83886080ull
#define U_WQK   84148224ull

__device__ __forceinline__ u16 f2bf(float f) {
    union { float f; unsigned u; } v; v.f = f;
    return (u16)((v.u + 0x7fffu + ((v.u >> 16) & 1u)) >> 16);
}
__device__ __forceinline__ float bf2f(u16 u) {
    union { unsigned u; float f; } v; v.u = ((unsigned)u) << 16;
    return v.f;
}
__device__ __forceinline__ void ld_async16(const u16* g, u16* l) {
    __builtin_amdgcn_global_load_lds(
        (const __attribute__((address_space(1))) void*)g,
        (__attribute__((address_space(3))) void*)l, 16, 0, 0);
}

// ---------------- K1: fused avg+max 3x3 pool ----------------
__global__ __launch_bounds__(256) void pool_kernel(const float* __restrict__ x,
                                                   float* __restrict__ qp,
                                                   float* __restrict__ kp) {
    int idx = blockIdx.x * 256 + threadIdx.x;      // < 8388608
    int r = idx & 1023;
    int c = (idx >> 10) & 511;
    int b = idx >> 19;
    int i = r >> 5, j = r & 31;
    const float* p = x + b * 4718592 + c * 9216 + (3 * i) * 96 + 3 * j;
    float s = 0.f, mx = -INFINITY;
    #pragma unroll
    for (int di = 0; di < 3; ++di)
        #pragma unroll
        for (int dj = 0; dj < 3; ++dj) {
            float v = p[di * 96 + dj];
            s += v; mx = fmaxf(mx, v);
        }
    qp[idx] = s * (1.f / 9.f);
    kp[idx] = mx;
}

// ---------------- T: tiled fp32->bf16 transpose (per-batch 524288 elems) ----------------
__global__ __launch_bounds__(256) void transpose_cvt(const float* __restrict__ in,
                                                     u16* __restrict__ out,
                                                     int inRows, int inCols) {
    __shared__ float tile[32][33];
    const float* src = in + (size_t)blockIdx.z * 524288;
    u16* dst = out + (size_t)blockIdx.z * 524288;
    int c0 = blockIdx.x * 32, r0 = blockIdx.y * 32;
    int tx = threadIdx.x & 31, ty = threadIdx.x >> 5;
    #pragma unroll
    for (int it = 0; it < 4; ++it)
        tile[ty + it * 8][tx] = src[(size_t)(r0 + ty + it * 8) * inCols + c0 + tx];
    __syncthreads();
    #pragma unroll
    for (int it = 0; it < 4; ++it)
        dst[(size_t)(c0 + ty + it * 8) * inRows + r0 + tx] = f2bf(tile[tx][ty + it * 8]);
}

__global__ __launch_bounds__(256) void cvt_bf16(const float* __restrict__ in,
                                                u16* __restrict__ out, int n) {
    int i = blockIdx.x * 256 + threadIdx.x;
    if (i < n) out[i] = f2bf(in[i]);
}

__global__ __launch_bounds__(256) void zero_f32(float* __restrict__ p, int n) {
    int i = blockIdx.x * 256 + threadIdx.x;
    if (i < n) p[i] = 0.f;
}

// ---------------- shared MFMA 128x128 BT-GEMM body (m97 structure) ----------------
// C[m][n] += sum_k A[m][k]*B[n][k]; A,B row-major bf16, 128 rows each, K%32==0.
__device__ __forceinline__ void gemm_bt_body(const u16* __restrict__ A, int ldA,
                                             const u16* __restrict__ B, int ldB, int K,
                                             u16* As, u16* Bs, floatx4 (&acc)[4][4]) {
    const int tid = threadIdx.x;
    const int lane = tid & 63;
    const int wv = tid >> 6;
    const int wm = (wv & 1) * 64, wn = (wv >> 1) * 64;
    const u16* ga0 = A + (size_t)(tid >> 2) * ldA + (tid & 3) * 8;
    const u16* ga1 = A + (size_t)((tid >> 2) + 64) * ldA + (tid & 3) * 8;
    const u16* gb0 = B + (size_t)(tid >> 2) * ldB + (tid & 3) * 8;
    const u16* gb1 = B + (size_t)((tid >> 2) + 64) * ldB + (tid & 3) * 8;
    u16* la0 = As + tid * 8;
    u16* la1 = As + (tid + 256) * 8;
    u16* lb0 = Bs + tid * 8;
    u16* lb1 = Bs + (tid + 256) * 8;
    const int arow = (lane & 15) * 32 + (lane >> 4) * 8;   // row-in-tile*32 + quad*8
    for (int k0 = 0; k0 < K; k0 += 32) {
        ld_async16(ga0 + k0, la0);
        ld_async16(ga1 + k0, la1);
        ld_async16(gb0 + k0, lb0);
        ld_async16(gb1 + k0, lb1);
        __syncthreads();
        bf16x8 af[4], bfr[4];
        #pragma unroll
        for (int i = 0; i < 4; ++i)
            af[i] = *(const bf16x8*)&As[(wm + i * 16) * 32 + arow];
        #pragma unroll
        for (int j = 0; j < 4; ++j)
            bfr[j] = *(const bf16x8*)&Bs[(wn + j * 16) * 32 + arow];
        #pragma unroll
        for (int i = 0; i < 4; ++i)
            #pragma unroll
            for (int j = 0; j < 4; ++j)
                acc[i][j] = __builtin_amdgcn_mfma_f32_16x16x32_bf16(af[i], bfr[j], acc[i][j], 0, 0, 0);
        __syncthreads();
    }
}

// ---------------- G1: vp[o][r] = bv[o] + sum_c Wv[o][c]*qpool[c][r] ----------------
__global__ __launch_bounds__(256) void vpool_mfma(const u16* __restrict__ Wv_bf,
                                                  const float* __restrict__ bv,
                                                  const u16* __restrict__ qpT_v,
                                                  u16* __restrict__ vp_bf) {
    __shared__ __align__(16) u16 As[4096], Bs[4096];
    floatx4 acc[4][4] = {};
    const int m0 = blockIdx.y * 128, n0 = blockIdx.x * 128, b = blockIdx.z;
    gemm_bt_body(Wv_bf + (size_t)m0 * 512, 512,
                 qpT_v + (size_t)b * 524288 + (size_t)n0 * 512, 512, 512, As, Bs, acc);
    const int tid = threadIdx.x, lane = tid & 63, wv = tid >> 6;
    const int wm = (wv & 1) * 64, wn = (wv >> 1) * 64, col = lane & 15, quad = lane >> 4;
    u16* outb = vp_bf + (size_t)b * 524288;
    #pragma unroll
    for (int i = 0; i < 4; ++i)
        #pragma unroll
        for (int r = 0; r < 4; ++r) {
            int m = m0 + wm + i * 16 + quad * 4 + r;
            float bias = bv[m];
            #pragma unroll
            for (int j = 0; j < 4; ++j) {
                int n = n0 + wn + j * 16 + col;
                outb[(size_t)m * 1024 + n] = f2bf(acc[i][j][r] + bias);
            }
        }
}

// ---------------- G2: proj[c][e] = bqk[h][e] + sum_d headsT[c][d]*Wqk[h][e][d] ----------------
__global__ __launch_bounds__(256) void proj_mfma(const u16* __restrict__ qpT_p,
                                                 const u16* __restrict__ kpT_p,
                                                 const u16* __restrict__ Wqk_bf,
                                                 const float* __restrict__ bqk,
                                                 u16* __restrict__ pq_bf,
                                                 u16* __restrict__ pk_bf) {
    __shared__ __align__(16) u16 As[4096], Bs[4096];
    floatx4 acc[4][4] = {};
    const int z = blockIdx.y;
    const int b = z >> 4, h = (z >> 1) & 7, src = z & 1;
    const int m0 = blockIdx.x * 128;
    const u16* P = (src ? kpT_p : qpT_p) + (size_t)b * 524288 + (size_t)m0 * 1024 + h * 128;
    gemm_bt_body(P, 1024, Wqk_bf + h * 16384, 128, 128, As, Bs, acc);
    const int tid = threadIdx.x, lane = tid & 63, wv = tid >> 6;
    const int wm = (wv & 1) * 64, wn = (wv >> 1) * 64, col = lane & 15, quad = lane >> 4;
    u16* outp = (src ? pk_bf : pq_bf) + (size_t)(b * 8 + h) * 65536 + (size_t)m0 * 128;
    #pragma unroll
    for (int i = 0; i < 4; ++i)
        #pragma unroll
        for (int r = 0; r < 4; ++r) {
            int m = wm + i * 16 + quad * 4 + r;
            #pragma unroll
            for (int j = 0; j < 4; ++j) {
                int n = wn + j * 16 + col;
                outp[(size_t)m * 128 + n] = f2bf(acc[i][j][r] + bqk[h * 128 + n]);
            }
        }
}

// ---------------- gate path (tiny) ----------------
__global__ __launch_bounds__(128) void kbar_kernel(const u16* __restrict__ pk_bf,
                                                   float* __restrict__ kbar) {
    int bh = blockIdx.x, d = threadIdx.x;
    const u16* p = pk_bf + (size_t)bh * 65536 + d;
    float s = 0.f;
    for (int e = 0; e < 512; ++e) s += bf2f(p[e * 128]);
    kbar[bh * 128 + d] = s * (1.f / 512.f);
}

__global__ __launch_bounds__(256) void mrow_kernel(const u16* __restrict__ pq_bf,
                                                   const float* __restrict__ kbar,
                                                   float* __restrict__ mrow) {
    __shared__ float kb[128];
    int bh = blockIdx.x, tid = threadIdx.x;
    if (tid < 128) kb[tid] = kbar[bh * 128 + tid];
    __syncthreads();
    for (int c = tid; c < 512; c += 256) {
        const u16* q = pq_bf + (size_t)bh * 65536 + c * 128;
        float s = 0.f;
        #pragma unroll 8
        for (int d = 0; d < 128; ++d) s += bf2f(q[d]) * kb[d];
        mrow[bh * 512 + c] = s;
    }
}

__global__ __launch_bounds__(256) void gate_kernel(const float* __restrict__ mrow,
                                                   const float* __restrict__ Wp,
                                                   const float* __restrict__ bp,
                                                   float* __restrict__ ipw) {
    __shared__ float ms[512];
    int bh = blockIdx.x, tid = threadIdx.x;
    for (int c = tid; c < 512; c += 256) ms[c] = mrow[bh * 512 + c];
    __syncthreads();
    for (int c2 = tid; c2 < 512; c2 += 256) {
        const float* wr = Wp + c2 * 512;
        float a = bp[c2];
        #pragma unroll 8
        for (int c = 0; c < 512; ++c) a += ms[c] * wr[c];
        float pg = 1.f / (1.f + expf(-a));
        ipw[bh * 512 + c2] = exp2f(-7.f * (0.5f + pg));   // 128^-(0.5+p)
    }
}

// ---------------- G3: e[c][n] = exp(ipw[c]*sum_d q[c][d]*k[n][d]); rowsum atomics ----------------
__global__ __launch_bounds__(256) void scores_mfma(const u16* __restrict__ pq_bf,
                                                   const u16* __restrict__ pk_bf,
                                                   const float* __restrict__ ipw,
                                                   u16* __restrict__ e_bf,
                                                   float* __restrict__ rowsum) {
    __shared__ __align__(16) u16 As[4096], Bs[4096];
    floatx4 acc[4][4] = {};
    const int n0 = blockIdx.x * 128, m0 = blockIdx.y * 128, bh = blockIdx.z;
    gemm_bt_body(pq_bf + (size_t)bh * 65536 + (size_t)m0 * 128, 128,
                 pk_bf + (size_t)bh * 65536 + (size_t)n0 * 128, 128, 128, As, Bs, acc);
    const int tid = threadIdx.x, lane = tid & 63, wv = tid >> 6;
    const int wm = (wv & 1) * 64, wn = (wv >> 1) * 64, col = lane & 15, quad = lane >> 4;
    u16* ebase = e_bf + (size_t)bh * 262144;
    float* rs = rowsum + bh * 512;
    #pragma unroll
    for (int i = 0; i < 4; ++i)
        #pragma unroll
        for (int r = 0; r < 4; ++r) {
            int m = m0 + wm + i * 16 + quad * 4 + r;
            float sc = ipw[(size_t)bh * 512 + m];
            float p = 0.f;
            #pragma unroll
            for (int j = 0; j < 4; ++j) {
                int n = n0 + wn + j * 16 + col;
                u16 eb = f2bf(expf(acc[i][j][r] * sc));
                ebase[(size_t)m * 512 + n] = eb;
                p += bf2f(eb);
            }
            #pragma unroll
            for (int o = 8; o; o >>= 1) p += __shfl_xor(p, o);
            if (col == 0) atomicAdd(&rs[m], p);
        }
}

// ---------------- G4: out[b,s=h*128+d,c] = qp + mult * (sum_e v[d][e]*ehat[c][e]) / rowsum[c] ----------------
__global__ __launch_bounds__(256) void attn_out_mfma(const u16* __restrict__ vp_bf,
                                                     const u16* __restrict__ e_bf,
                                                     const float* __restrict__ rowsum,
                                                     const float* __restrict__ qp,
                                                     float* __restrict__ outp,
                                                     const int* __restrict__ wgt) {
    __shared__ __align__(16) u16 As[4096], Bs[4096];
    floatx4 acc[4][4] = {};
    const int n0 = blockIdx.x * 128, bh = blockIdx.y;
    const int b = bh >> 3, h = bh & 7;
    gemm_bt_body(vp_bf + (size_t)b * 524288 + (size_t)h * 65536, 512,
                 e_bf + (size_t)bh * 262144 + (size_t)n0 * 512, 512, 512, As, Bs, acc);
    const int tid = threadIdx.x, lane = tid & 63, wv = tid >> 6;
    const int wm = (wv & 1) * 64, wn = (wv >> 1) * 64, col = lane & 15, quad = lane >> 4;
    const float mult = 1.f + (float)wgt[0];
    #pragma unroll
    for (int j = 0; j < 4; ++j) {
        int n = n0 + wn + j * 16 + col;                 // c
        float inv = mult / rowsum[bh * 512 + n];
        #pragma unroll
        for (int i = 0; i < 4; ++i)
            #pragma unroll
            for (int r = 0; r < 4; ++r) {
                int m = wm + i * 16 + quad * 4 + r;     // d
                size_t o = (size_t)b * 524288 + (size_t)(h * 128 + m) * 512 + n;
                outp[o] = qp[o] + acc[i][j][r] * inv;
            }
    }
}

extern "C" void kernel_launch(void* const* d_in, const int* in_sizes, int n_in,
                              void* d_out, int out_size, void* d_ws, size_t ws_size,
                              hipStream_t stream) {
    const float* x   = (const float*)d_in[0];
    const float* Wqk = (const float*)d_in[1];
    const float* bqk = (const float*)d_in[2];
    const float* Wp  = (const float*)d_in[3];
    const float* bp  = (const float*)d_in[4];
    const float* Wv  = (const float*)d_in[5];
    const float* bv  = (const float*)d_in[6];
    const int*   wgt = (const int*)d_in[7];
    float* out = (float*)d_out;

    float* ws = (float*)d_ws;
    float* qp   = ws + F_QP;
    float* kp   = ws + F_KP;
    float* kbar = ws + F_KBAR;
    float* mrow = ws + F_MROW;
    float* ipw  = ws + F_IPW;
    float* rs   = ws + F_RS;
    u16* ub = (u16*)(ws + F_END);
    u16* qpT_v  = ub + U_QPT_V;
    u16* qpT_p  = ub + U_QPT_P;
    u16* kpT_p  = ub + U_KPT_P;
    u16* pq_bf  = ub + U_PQ;
    u16* pk_bf  = ub + U_PK;
    u16* vp_bf  = ub + U_VP;
    u16* e_bf   = ub + U_E;
    u16* Wv_bf  = ub + U_WV;
    u16* Wqk_bf = ub + U_WQK;

    pool_kernel<<<32768, 256, 0, stream>>>(x, qp, kp);
    transpose_cvt<<<dim3(32, 16, 16), 256, 0, stream>>>(qp, qpT_v, 512, 1024);
    transpose_cvt<<<dim3(16, 32, 16), 256, 0, stream>>>(qp, qpT_p, 1024, 512);
    transpose_cvt<<<dim3(16, 32, 16), 256, 0, stream>>>(kp, kpT_p, 1024, 512);
    cvt_bf16<<<1024, 256, 0, stream>>>(Wv, Wv_bf, 262144);
    cvt_bf16<<<512, 256, 0, stream>>>(Wqk, Wqk_bf, 131072);
    zero_f32<<<256, 256, 0, stream>>>(rs, 65536);

    vpool_mfma<<<dim3(8, 4, 16), 256, 0, stream>>>(Wv_bf, bv, qpT_v, vp_bf);
    proj_mfma<<<dim3(4, 256), 256, 0, stream>>>(qpT_p, kpT_p, Wqk_bf, bqk, pq_bf, pk_bf);
    kbar_kernel<<<128, 128, 0, stream>>>(pk_bf, kbar);
    mrow_kernel<<<128, 256, 0, stream>>>(pq_bf, kbar, mrow);
    gate_kernel<<<128, 256, 0, stream>>>(mrow, Wp, bp, ipw);
    scores_mfma<<<dim3(4, 4, 128), 256, 0, stream>>>(pq_bf, pk_bf, ipw, e_bf, rs);
    attn_out_mfma<<<dim3(4, 128), 256, 0, stream>>>(vp_bf, e_bf, rs, qp, out, wgt);
}

// Round 3
// 596.777 us; speedup vs baseline: 1.5996x; 1.0606x over previous
//
#include <hip/hip_runtime.h>
#include <math.h>

// Problem: B=16, C=512, R=32, PS=3, HN=8, D=128, H=W=96.
typedef unsigned short u16;
typedef short bf16x8 __attribute__((ext_vector_type(8)));
typedef float floatx4 __attribute__((ext_vector_type(4)));

// ---- workspace layout ----
// floats:
#define F_QP   0ull            // [b][c=512][r=1024] fp32 pooled avg (residual + src)
#define F_IPW  8388608ull      // [bh][512]
#define F_WPT  8454144ull      // WpT [c][c2] 512x512
#define F_END  8716288ull
// ushorts (base = (u16*)(ws + F_END)):
#define U_QPT_V 0ull           // [b][r=1024][c=512]
#define U_QPT_P 8388608ull     // [b][cc=512][s=1024]
#define U_KPT_P 16777216ull
#define U_PQ    25165824ull    // [bh][c=512][e=128]
#define U_PK    33554432ull
#define U_VP    41943040ull    // [b] flat [o=512][r=1024]
#define U_WV    50331648ull
#define U_WQK   50593792ull

__device__ __forceinline__ u16 f2bf(float f) {
    union { float f; unsigned u; } v; v.f = f;
    return (u16)((v.u + 0x7fffu + ((v.u >> 16) & 1u)) >> 16);
}
__device__ __forceinline__ float bf2f(u16 u) {
    union { unsigned u; float f; } v; v.u = ((unsigned)u) << 16;
    return v.f;
}
__device__ __forceinline__ void ld_async16(const u16* g, u16* l) {
    __builtin_amdgcn_global_load_lds(
        (const __attribute__((address_space(1))) void*)g,
        (__attribute__((address_space(3))) void*)l, 16, 0, 0);
}

// ---------------- K1: fused 3x3 avg+max pool + bf16 transposes ----------------
// Replaces pool + 3 transpose_cvt kernels. Writes qp fp32 [c][r], qpT_v bf16 [r][c],
// qpT_p/kpT_p bf16 [cc][s] (s = 2c + (r>>9), cc = r&511).
__global__ __launch_bounds__(256) void pool_fused(const float* __restrict__ x,
                                                  float* __restrict__ qp,
                                                  u16* __restrict__ qpT_v,
                                                  u16* __restrict__ qpT_p,
                                                  u16* __restrict__ kpT_p) {
    __shared__ float Tq[32][33], Tk[32][33];
    const int tid = threadIdx.x;
    const int i  = blockIdx.x;        // pooled row 0..31
    const int c0 = blockIdx.y * 32;   // channel base
    const int b  = blockIdx.z;
    const int j  = tid & 31, cg = tid >> 5;
    #pragma unroll
    for (int p = 0; p < 4; ++p) {
        int cl = p * 8 + cg;
        const float* px = x + (size_t)b * 4718592 + (size_t)(c0 + cl) * 9216 + (3 * i) * 96 + 3 * j;
        float s = 0.f, mx = -INFINITY;
        #pragma unroll
        for (int di = 0; di < 3; ++di)
            #pragma unroll
            for (int dj = 0; dj < 3; ++dj) {
                float v = px[di * 96 + dj];
                s += v; mx = fmaxf(mx, v);
            }
        float q = s * (1.f / 9.f);
        Tq[cl][j] = q; Tk[cl][j] = mx;
        qp[(size_t)b * 524288 + (size_t)(c0 + cl) * 1024 + i * 32 + j] = q;
    }
    __syncthreads();
    const int cl = tid & 31, jq = tid >> 5;
    const int rh = i >> 4;
    const int s2 = (c0 + cl) * 2 + rh;
    #pragma unroll
    for (int jj = 0; jj < 4; ++jj) {
        int jw = jq + jj * 8;
        int rr = i * 32 + jw;
        int cc = rr & 511;
        u16 qb = f2bf(Tq[cl][jw]);
        u16 kb = f2bf(Tk[cl][jw]);
        qpT_v[(size_t)b * 524288 + (size_t)rr * 512 + c0 + cl] = qb;
        qpT_p[(size_t)b * 524288 + (size_t)cc * 1024 + s2] = qb;
        kpT_p[(size_t)b * 524288 + (size_t)cc * 1024 + s2] = kb;
    }
}

// ---------------- K2: weight casts (merged) ----------------
__global__ __launch_bounds__(256) void cvt_w(const float* __restrict__ Wv,
                                             const float* __restrict__ Wqk,
                                             u16* __restrict__ Wv_bf,
                                             u16* __restrict__ Wqk_bf) {
    int i = blockIdx.x * 256 + threadIdx.x;
    if (i < 262144) Wv_bf[i] = f2bf(Wv[i]);
    else if (i < 393216) Wqk_bf[i - 262144] = f2bf(Wqk[i - 262144]);
}

// ---------------- K3: WpT[c][c2] = Wp[c2][c] (fp32) ----------------
__global__ __launch_bounds__(256) void transpose_wp(const float* __restrict__ in,
                                                    float* __restrict__ out) {
    __shared__ float t[32][33];
    int x0 = blockIdx.x * 32, y0 = blockIdx.y * 32;
    int tx = threadIdx.x & 31, ty = threadIdx.x >> 5;
    #pragma unroll
    for (int it = 0; it < 4; ++it)
        t[ty + it * 8][tx] = in[(size_t)(y0 + ty + it * 8) * 512 + x0 + tx];
    __syncthreads();
    #pragma unroll
    for (int it = 0; it < 4; ++it)
        out[(size_t)(x0 + ty + it * 8) * 512 + y0 + tx] = t[tx][ty + it * 8];
}

// ---------------- shared MFMA 128x128 BT-GEMM body (m97 structure) ----------------
__device__ __forceinline__ void gemm_bt_body(const u16* __restrict__ A, int ldA,
                                             const u16* __restrict__ B, int ldB, int K,
                                             u16* As, u16* Bs, floatx4 (&acc)[4][4]) {
    const int tid = threadIdx.x;
    const int lane = tid & 63;
    const int wv = tid >> 6;
    const int wm = (wv & 1) * 64, wn = (wv >> 1) * 64;
    const u16* ga0 = A + (size_t)(tid >> 2) * ldA + (tid & 3) * 8;
    const u16* ga1 = A + (size_t)((tid >> 2) + 64) * ldA + (tid & 3) * 8;
    const u16* gb0 = B + (size_t)(tid >> 2) * ldB + (tid & 3) * 8;
    const u16* gb1 = B + (size_t)((tid >> 2) + 64) * ldB + (tid & 3) * 8;
    u16* la0 = As + tid * 8;
    u16* la1 = As + (tid + 256) * 8;
    u16* lb0 = Bs + tid * 8;
    u16* lb1 = Bs + (tid + 256) * 8;
    const int arow = (lane & 15) * 32 + (lane >> 4) * 8;
    for (int k0 = 0; k0 < K; k0 += 32) {
        ld_async16(ga0 + k0, la0);
        ld_async16(ga1 + k0, la1);
        ld_async16(gb0 + k0, lb0);
        ld_async16(gb1 + k0, lb1);
        __syncthreads();
        bf16x8 af[4], bfr[4];
        #pragma unroll
        for (int i = 0; i < 4; ++i)
            af[i] = *(const bf16x8*)&As[(wm + i * 16) * 32 + arow];
        #pragma unroll
        for (int j = 0; j < 4; ++j)
            bfr[j] = *(const bf16x8*)&Bs[(wn + j * 16) * 32 + arow];
        #pragma unroll
        for (int i = 0; i < 4; ++i)
            #pragma unroll
            for (int j = 0; j < 4; ++j)
                acc[i][j] = __builtin_amdgcn_mfma_f32_16x16x32_bf16(af[i], bfr[j], acc[i][j], 0, 0, 0);
        __syncthreads();
    }
}

// ---------------- K4: vp[o][r] = bv[o] + sum_c Wv[o][c]*qpool[c][r] ----------------
__global__ __launch_bounds__(256) void vpool_mfma(const u16* __restrict__ Wv_bf,
                                                  const float* __restrict__ bv,
                                                  const u16* __restrict__ qpT_v,
                                                  u16* __restrict__ vp_bf) {
    __shared__ __align__(16) u16 As[4096], Bs[4096];
    floatx4 acc[4][4] = {};
    const int m0 = blockIdx.y * 128, n0 = blockIdx.x * 128, b = blockIdx.z;
    gemm_bt_body(Wv_bf + (size_t)m0 * 512, 512,
                 qpT_v + (size_t)b * 524288 + (size_t)n0 * 512, 512, 512, As, Bs, acc);
    const int tid = threadIdx.x, lane = tid & 63, wv = tid >> 6;
    const int wm = (wv & 1) * 64, wn = (wv >> 1) * 64, col = lane & 15, quad = lane >> 4;
    u16* outb = vp_bf + (size_t)b * 524288;
    #pragma unroll
    for (int i = 0; i < 4; ++i)
        #pragma unroll
        for (int r = 0; r < 4; ++r) {
            int m = m0 + wm + i * 16 + quad * 4 + r;
            float bias = bv[m];
            #pragma unroll
            for (int j = 0; j < 4; ++j) {
                int n = n0 + wn + j * 16 + col;
                outb[(size_t)m * 1024 + n] = f2bf(acc[i][j][r] + bias);
            }
        }
}

// ---------------- K5: proj[c][e] = bqk[h][e] + sum_d headsT[c][d]*Wqk[h][e][d] ----------------
__global__ __launch_bounds__(256) void proj_mfma(const u16* __restrict__ qpT_p,
                                                 const u16* __restrict__ kpT_p,
                                                 const u16* __restrict__ Wqk_bf,
                                                 const float* __restrict__ bqk,
                                                 u16* __restrict__ pq_bf,
                                                 u16* __restrict__ pk_bf) {
    __shared__ __align__(16) u16 As[4096], Bs[4096];
    floatx4 acc[4][4] = {};
    const int z = blockIdx.y;
    const int b = z >> 4, h = (z >> 1) & 7, src = z & 1;
    const int m0 = blockIdx.x * 128;
    const u16* P = (src ? kpT_p : qpT_p) + (size_t)b * 524288 + (size_t)m0 * 1024 + h * 128;
    gemm_bt_body(P, 1024, Wqk_bf + h * 16384, 128, 128, As, Bs, acc);
    const int tid = threadIdx.x, lane = tid & 63, wv = tid >> 6;
    const int wm = (wv & 1) * 64, wn = (wv >> 1) * 64, col = lane & 15, quad = lane >> 4;
    u16* outp = (src ? pk_bf : pq_bf) + (size_t)(b * 8 + h) * 65536 + (size_t)m0 * 128;
    #pragma unroll
    for (int i = 0; i < 4; ++i)
        #pragma unroll
        for (int r = 0; r < 4; ++r) {
            int m = wm + i * 16 + quad * 4 + r;
            #pragma unroll
            for (int j = 0; j < 4; ++j) {
                int n = wn + j * 16 + col;
                outp[(size_t)m * 128 + n] = f2bf(acc[i][j][r] + bqk[h * 128 + n]);
            }
        }
}

// ---------------- K6: fused kbar -> mrow -> gate (per bh) ----------------
__global__ __launch_bounds__(256) void gate_fused(const u16* __restrict__ pq_bf,
                                                  const u16* __restrict__ pk_bf,
                                                  const float* __restrict__ WpT,
                                                  const float* __restrict__ bp,
                                                  float* __restrict__ ipw) {
    __shared__ float sp[256];
    __shared__ float kb[128];
    __shared__ float ms[512];
    const int bh = blockIdx.x, tid = threadIdx.x;
    const u16* pkb = pk_bf + (size_t)bh * 65536;
    const u16* pqb = pq_bf + (size_t)bh * 65536;
    {   // kbar partials: coalesced rows (lanes span d)
        int d = tid & 127, half = tid >> 7;
        const u16* p = pkb + (size_t)(half * 256) * 128 + d;
        float s = 0.f;
        #pragma unroll 8
        for (int e = 0; e < 256; ++e) s += bf2f(p[(size_t)e * 128]);
        sp[tid] = s;
    }
    __syncthreads();
    if (tid < 128) kb[tid] = (sp[tid] + sp[tid + 128]) * (1.f / 512.f);
    __syncthreads();
    for (int cc = tid; cc < 512; cc += 256) {
        const u16* q = pqb + (size_t)cc * 128;
        float s = 0.f;
        #pragma unroll 8
        for (int d = 0; d < 128; ++d) s += bf2f(q[d]) * kb[d];
        ms[cc] = s;
    }
    __syncthreads();
    for (int c2 = tid; c2 < 512; c2 += 256) {
        float a = bp[c2];
        #pragma unroll 4
        for (int c = 0; c < 512; ++c) a += ms[c] * WpT[(size_t)c * 512 + c2];
        float pg = 1.f / (1.f + __expf(-a));
        ipw[bh * 512 + c2] = exp2f(-7.f * (0.5f + pg));   // 128^-(0.5+p)
    }
}

// ---------------- K7: flash-fused scores->exp->rowsum->PV->residual ----------------
// Block: (m0 c-slice of 128, bh). e-tile kept in LDS; out[d][c] orientation (coalesced).
__global__ __launch_bounds__(256, 2) void flash_mfma(const u16* __restrict__ pq_bf,
                                                     const u16* __restrict__ pk_bf,
                                                     const u16* __restrict__ vp_bf,
                                                     const float* __restrict__ ipw,
                                                     const float* __restrict__ qp,
                                                     float* __restrict__ outp,
                                                     const int* __restrict__ wgt) {
    __shared__ __align__(16) u16 As[4096];
    __shared__ __align__(16) u16 Bs[4096];
    __shared__ __align__(16) u16 Et[128 * 136];
    __shared__ float rsS[128];
    __shared__ float ipwS[128];
    const int tid = threadIdx.x, lane = tid & 63, wv = tid >> 6;
    const int wm = (wv & 1) * 64, wn = (wv >> 1) * 64, col = lane & 15, quad = lane >> 4;
    const int bh = blockIdx.y, b = bh >> 3, h = bh & 7;
    const int m0 = blockIdx.x * 128;
    if (tid < 128) { rsS[tid] = 0.f; ipwS[tid] = ipw[bh * 512 + m0 + tid]; }
    const u16* Aq = pq_bf + (size_t)bh * 65536 + (size_t)m0 * 128;
    const u16* Bk = pk_bf + (size_t)bh * 65536;
    const u16* Av = vp_bf + (size_t)b * 524288 + (size_t)h * 65536;
    const int srow = tid >> 2, scol = (tid & 3) * 8;
    u16 *la0 = As + tid * 8, *la1 = As + (tid + 256) * 8;
    u16 *lb0 = Bs + tid * 8, *lb1 = Bs + (tid + 256) * 8;
    const int arow = col * 32 + quad * 8;
    floatx4 accP[4][4] = {};
    __syncthreads();

    for (int n0 = 0; n0 < 512; n0 += 128) {
        // ---- score GEMM (rows c, cols e-chunk), K=128 ----
        floatx4 accS[4][4] = {};
        for (int k0 = 0; k0 < 128; k0 += 32) {
            ld_async16(Aq + (size_t)srow * 128 + k0 + scol, la0);
            ld_async16(Aq + (size_t)(srow + 64) * 128 + k0 + scol, la1);
            ld_async16(Bk + (size_t)(n0 + srow) * 128 + k0 + scol, lb0);
            ld_async16(Bk + (size_t)(n0 + srow + 64) * 128 + k0 + scol, lb1);
            __syncthreads();
            bf16x8 af[4], bfr[4];
            #pragma unroll
            for (int i = 0; i < 4; ++i) af[i] = *(const bf16x8*)&As[(wm + i * 16) * 32 + arow];
            #pragma unroll
            for (int j = 0; j < 4; ++j) bfr[j] = *(const bf16x8*)&Bs[(wn + j * 16) * 32 + arow];
            #pragma unroll
            for (int i = 0; i < 4; ++i)
                #pragma unroll
                for (int j = 0; j < 4; ++j)
                    accS[i][j] = __builtin_amdgcn_mfma_f32_16x16x32_bf16(af[i], bfr[j], accS[i][j], 0, 0, 0);
            __syncthreads();
        }
        // ---- epilogue: exp -> Et (LDS), rowsum -> rsS ----
        #pragma unroll
        for (int i = 0; i < 4; ++i)
            #pragma unroll
            for (int r = 0; r < 4; ++r) {
                int ml = wm + i * 16 + quad * 4 + r;
                float sc = ipwS[ml];
                float p = 0.f;
                #pragma unroll
                for (int j = 0; j < 4; ++j) {
                    float e = __expf(accS[i][j][r] * sc);
                    p += e;
                    Et[ml * 136 + wn + j * 16 + col] = f2bf(e);
                }
                #pragma unroll
                for (int o = 8; o; o >>= 1) p += __shfl_xor(p, o);
                if (col == 0) atomicAdd(&rsS[ml], p);
            }
        __syncthreads();
        // ---- PV partial: A = v (rows d), B = Et (rows c), K = 128 ----
        for (int k0 = 0; k0 < 128; k0 += 32) {
            ld_async16(Av + (size_t)srow * 512 + n0 + k0 + scol, la0);
            ld_async16(Av + (size_t)(srow + 64) * 512 + n0 + k0 + scol, la1);
            __syncthreads();
            bf16x8 af[4], bfr[4];
            #pragma unroll
            for (int i = 0; i < 4; ++i) af[i] = *(const bf16x8*)&As[(wm + i * 16) * 32 + arow];
            #pragma unroll
            for (int j = 0; j < 4; ++j) bfr[j] = *(const bf16x8*)&Et[(wn + j * 16 + col) * 136 + k0 + quad * 8];
            #pragma unroll
            for (int i = 0; i < 4; ++i)
                #pragma unroll
                for (int j = 0; j < 4; ++j)
                    accP[i][j] = __builtin_amdgcn_mfma_f32_16x16x32_bf16(af[i], bfr[j], accP[i][j], 0, 0, 0);
            __syncthreads();
        }
    }
    const float mult = 1.f + (float)wgt[0];
    #pragma unroll
    for (int j = 0; j < 4; ++j) {
        int nl = wn + j * 16 + col;                 // c local
        float inv = mult / rsS[nl];
        #pragma unroll
        for (int i = 0; i < 4; ++i)
            #pragma unroll
            for (int r = 0; r < 4; ++r) {
                int d = wm + i * 16 + quad * 4 + r;
                size_t o = (size_t)b * 524288 + (size_t)(h * 128 + d) * 512 + m0 + nl;
                outp[o] = qp[o] + accP[i][j][r] * inv;
            }
    }
}

extern "C" void kernel_launch(void* const* d_in, const int* in_sizes, int n_in,
                              void* d_out, int out_size, void* d_ws, size_t ws_size,
                              hipStream_t stream) {
    const float* x   = (const float*)d_in[0];
    const float* Wqk = (const float*)d_in[1];
    const float* bqk = (const float*)d_in[2];
    const float* Wp  = (const float*)d_in[3];
    const float* bp  = (const float*)d_in[4];
    const float* Wv  = (const float*)d_in[5];
    const float* bv  = (const float*)d_in[6];
    const int*   wgt = (const int*)d_in[7];
    float* out = (float*)d_out;

    float* ws = (float*)d_ws;
    float* qp  = ws + F_QP;
    float* ipw = ws + F_IPW;
    float* WpT = ws + F_WPT;
    u16* ub = (u16*)(ws + F_END);
    u16* qpT_v  = ub + U_QPT_V;
    u16* qpT_p  = ub + U_QPT_P;
    u16* kpT_p  = ub + U_KPT_P;
    u16* pq_bf  = ub + U_PQ;
    u16* pk_bf  = ub + U_PK;
    u16* vp_bf  = ub + U_VP;
    u16* Wv_bf  = ub + U_WV;
    u16* Wqk_bf = ub + U_WQK;

    pool_fused<<<dim3(32, 16, 16), 256, 0, stream>>>(x, qp, qpT_v, qpT_p, kpT_p);
    cvt_w<<<1536, 256, 0, stream>>>(Wv, Wqk, Wv_bf, Wqk_bf);
    transpose_wp<<<dim3(16, 16), 256, 0, stream>>>(Wp, WpT);
    vpool_mfma<<<dim3(8, 4, 16), 256, 0, stream>>>(Wv_bf, bv, qpT_v, vp_bf);
    proj_mfma<<<dim3(4, 256), 256, 0, stream>>>(qpT_p, kpT_p, Wqk_bf, bqk, pq_bf, pk_bf);
    gate_fused<<<128, 256, 0, stream>>>(pq_bf, pk_bf, WpT, bp, ipw);
    flash_mfma<<<dim3(4, 128), 256, 0, stream>>>(pq_bf, pk_bf, vp_bf, ipw, qp, out, wgt);
}